// Round 7
// baseline (116.540 us; speedup 1.0000x reference)
//
#include <hip/hip_runtime.h>

// QPLayer: per-batch dual QP via 400 fixed PGD iterations — EXACT reference
// trajectory (R6 lesson: some problems are NOT converged at 400 iters, so the
// output is trajectory-dependent; alpha must stay 1/(2||S||_F) and iters 400).
// Math: q = b (x cancels), M = 2*A*A^T (rank 4), L = 2*||A^T A||_F + 1e-6,
//       alpha = 1/L, lam <- relu(lam - alpha*b - 2*alpha*A(A^T lam)), out = -A^T lam.
// Pre-scale: A' = sqrt(2*alpha)*A  =>  lam <- relu(lam - alpha*b - A'(A'^T lam)),
//       out = -(1/sc) * A'^T lam, sc = sqrt(2*alpha).
// Decomposition: 4 lanes/problem; lane j owns rows 8j..8j+7 + matching lam.
// Cross-lane: 2-stage DPP quad butterfly. 2048 waves = 2 waves/SIMD.
//
// R7 lever: packed fp32 (v_pk_fma_f32 / v_pk_add_f32, VOP3P 64-bit pairs) —
// 2 fp32 FMAs per instruction at the same issue rate. hipcc never forms these
// from scalar fmaf, so they are forced via inline asm on ext_vector_type(2).
// Static VALU/iter: 88 -> ~66. R5 counters (VALUBusy ~100%, 2 waves/SIMD)
// say issue-bound, so time should scale with instruction count.
// Pairing = k even/odd split per lane: rounding-order drift ~1e-7/iter,
// linear growth (nonexpansive map), R5 margin is 22x.

#define QP_ITERS 400

typedef float v2f __attribute__((ext_vector_type(2)));

__device__ __forceinline__ v2f pk_fma(v2f a, v2f b, v2f c) {
    v2f d;
    asm("v_pk_fma_f32 %0, %1, %2, %3" : "=v"(d) : "v"(a), "v"(b), "v"(c));
    return d;
}
__device__ __forceinline__ v2f pk_add(v2f a, v2f b) {
    v2f d;
    asm("v_pk_add_f32 %0, %1, %2" : "=v"(d) : "v"(a), "v"(b));
    return d;
}

template <int CTRL>
__device__ __forceinline__ float dpp_add(float v) {
    // fused v_add_f32_dpp (old = 0, bound_ctrl = 1)
    return v + __int_as_float(
        __builtin_amdgcn_update_dpp(0, __float_as_int(v), CTRL, 0xF, 0xF, true));
}

__device__ __forceinline__ float quad_sum(float v) {
    v = dpp_add<0xB1>(v);   // quad_perm(1,0,3,2): xor 1
    v = dpp_add<0x4E>(v);   // quad_perm(2,3,0,1): xor 2
    return v;
}

__global__ void __launch_bounds__(256)
__attribute__((amdgpu_waves_per_eu(1, 2)))
qp_pgd_kernel(
        const float* __restrict__ A,   // [nprob, 32, 4]
        const float* __restrict__ b,   // [nprob, 32]
        float* __restrict__ out,       // [nprob, 4]
        int nprob) {
    int t = blockIdx.x * blockDim.x + threadIdx.x;
    int p = t >> 2;          // problem index
    int j = t & 3;           // lane within quad
    if (p >= nprob) return;

    const float4* Ar = reinterpret_cast<const float4*>(A + (size_t)p * 128 + (size_t)j * 32);
    const float4* br = reinterpret_cast<const float4*>(b + (size_t)p * 32 + (size_t)j * 8);

    float ax[8], ay[8], az[8], aw[8];
#pragma unroll
    for (int k = 0; k < 8; ++k) {
        float4 r = Ar[k];
        ax[k] = r.x; ay[k] = r.y; az[k] = r.z; aw[k] = r.w;
    }
    float bb[8];
    {
        float4 b0 = br[0], b1 = br[1];
        bb[0] = b0.x; bb[1] = b0.y; bb[2] = b0.z; bb[3] = b0.w;
        bb[4] = b1.x; bb[5] = b1.y; bb[6] = b1.z; bb[7] = b1.w;
    }

    // ---- alpha = 1 / (2*||A^T A||_F + 1e-6)  (Frobenius only — reference) ----
    float s00 = 0.f, s01 = 0.f, s02 = 0.f, s03 = 0.f;
    float s11 = 0.f, s12 = 0.f, s13 = 0.f;
    float s22 = 0.f, s23 = 0.f, s33 = 0.f;
#pragma unroll
    for (int k = 0; k < 8; ++k) {
        s00 = fmaf(ax[k], ax[k], s00);
        s01 = fmaf(ax[k], ay[k], s01);
        s02 = fmaf(ax[k], az[k], s02);
        s03 = fmaf(ax[k], aw[k], s03);
        s11 = fmaf(ay[k], ay[k], s11);
        s12 = fmaf(ay[k], az[k], s12);
        s13 = fmaf(ay[k], aw[k], s13);
        s22 = fmaf(az[k], az[k], s22);
        s23 = fmaf(az[k], aw[k], s23);
        s33 = fmaf(aw[k], aw[k], s33);
    }
    s00 = quad_sum(s00); s01 = quad_sum(s01); s02 = quad_sum(s02); s03 = quad_sum(s03);
    s11 = quad_sum(s11); s12 = quad_sum(s12); s13 = quad_sum(s13);
    s22 = quad_sum(s22); s23 = quad_sum(s23); s33 = quad_sum(s33);
    float ssq = s00 * s00 + s11 * s11 + s22 * s22 + s33 * s33
              + 2.f * (s01 * s01 + s02 * s02 + s03 * s03
                     + s12 * s12 + s13 * s13 + s23 * s23);
    float L = 2.f * sqrtf(ssq) + 1e-6f;
    float alpha = 1.f / L;
    float sc = sqrtf(2.f * alpha);     // A' = sc * A
    float inv_sc = 1.f / sc;

    // ---- pack into pairs (rows 2i, 2i+1), pre-scaled; mc = -alpha*b ----
    v2f axp[4], ayp[4], azp[4], awp[4], mcp[4], lamp[4];
#pragma unroll
    for (int i = 0; i < 4; ++i) {
        axp[i] = (v2f){ax[2 * i] * sc, ax[2 * i + 1] * sc};
        ayp[i] = (v2f){ay[2 * i] * sc, ay[2 * i + 1] * sc};
        azp[i] = (v2f){az[2 * i] * sc, az[2 * i + 1] * sc};
        awp[i] = (v2f){aw[2 * i] * sc, aw[2 * i + 1] * sc};
        mcp[i] = (v2f){-alpha * bb[2 * i], -alpha * bb[2 * i + 1]};
        lamp[i] = (v2f){0.f, 0.f};
    }

    // ---- 400 PGD iterations ----
    for (int it = 0; it < QP_ITERS; ++it) {
        // u' = A'^T lam : 4 packed chains over 4 row-pairs
        v2f a0 = (v2f){0.f, 0.f}, a1 = (v2f){0.f, 0.f};
        v2f a2 = (v2f){0.f, 0.f}, a3 = (v2f){0.f, 0.f};
#pragma unroll
        for (int i = 0; i < 4; ++i) {
            a0 = pk_fma(axp[i], lamp[i], a0);
            a1 = pk_fma(ayp[i], lamp[i], a1);
            a2 = pk_fma(azp[i], lamp[i], a2);
            a3 = pk_fma(awp[i], lamp[i], a3);
        }
        float u0 = a0.x + a0.y, u1 = a1.x + a1.y;
        float u2 = a2.x + a2.y, u3 = a3.x + a3.y;
        u0 = quad_sum(u0); u1 = quad_sum(u1); u2 = quad_sum(u2); u3 = quad_sum(u3);
        float n0 = -u0, n1 = -u1, n2 = -u2, n3 = -u3;
        v2f U0 = (v2f){n0, n0}, U1 = (v2f){n1, n1};
        v2f U2 = (v2f){n2, n2}, U3 = (v2f){n3, n3};
        // lam = relu(lam - c - A'·u')  (packed per row-pair)
#pragma unroll
        for (int i = 0; i < 4; ++i) {
            v2f tt = pk_add(lamp[i], mcp[i]);
            tt = pk_fma(axp[i], U0, tt);
            tt = pk_fma(ayp[i], U1, tt);
            tt = pk_fma(azp[i], U2, tt);
            tt = pk_fma(awp[i], U3, tt);
            lamp[i].x = fmaxf(tt.x, 0.f);
            lamp[i].y = fmaxf(tt.y, 0.f);
        }
    }

    // ---- output: out = -(1/sc) * A'^T lam ----
    v2f a0 = (v2f){0.f, 0.f}, a1 = (v2f){0.f, 0.f};
    v2f a2 = (v2f){0.f, 0.f}, a3 = (v2f){0.f, 0.f};
#pragma unroll
    for (int i = 0; i < 4; ++i) {
        a0 = pk_fma(axp[i], lamp[i], a0);
        a1 = pk_fma(ayp[i], lamp[i], a1);
        a2 = pk_fma(azp[i], lamp[i], a2);
        a3 = pk_fma(awp[i], lamp[i], a3);
    }
    float u0 = a0.x + a0.y, u1 = a1.x + a1.y;
    float u2 = a2.x + a2.y, u3 = a3.x + a3.y;
    u0 = quad_sum(u0); u1 = quad_sum(u1); u2 = quad_sum(u2); u3 = quad_sum(u3);
    float r = (j & 1) ? ((j & 2) ? u3 : u1) : ((j & 2) ? u2 : u0);
    out[(size_t)p * 4 + j] = -r * inv_sc;
}

extern "C" void kernel_launch(void* const* d_in, const int* in_sizes, int n_in,
                              void* d_out, int out_size, void* d_ws, size_t ws_size,
                              hipStream_t stream) {
    const float* A = (const float*)d_in[0];
    // d_in[1] (x) cancels analytically and is unused.
    const float* b = (const float*)d_in[2];
    float* out = (float*)d_out;

    int nprob = in_sizes[2] / 32;          // B = 32768
    int threads = nprob * 4;               // 4 lanes per problem
    dim3 block(256);
    dim3 grid((threads + 255) / 256);
    hipLaunchKernelGGL(qp_pgd_kernel, grid, block, 0, stream, A, b, out, nprob);
}

// Round 8
// 93.233 us; speedup vs baseline: 1.2500x; 1.2500x over previous
//
#include <hip/hip_runtime.h>

// QPLayer: per-batch dual QP via 400 fixed PGD iterations — EXACT reference
// trajectory (R6: some problems are NOT converged at 400 iters -> output is
// trajectory-dependent; alpha stays 1/(2||S||_F + eps-ish), iters stay 400).
// Math: q = b (x cancels), M = 2*A*A^T, L = 2*||A^T A||_F + 1e-6, alpha = 1/L,
//   lam <- relu(lam - alpha*b - 2*alpha*A(A^T lam)),  out = -A^T lam.
// Pre-scale A' = sqrt(2*alpha)*A:  lam <- relu(lam - alpha*b - A'(A'^T lam)),
//   out = -(1/sc) A'^T lam, sc = sqrt(2*alpha).
// Decomposition: 4 lanes/problem; lane j owns rows 8j..8j+7 (as 4 row-pairs)
// + matching lam. Cross-lane: 2-stage DPP quad butterfly. 2048 waves = 2/SIMD.
//
// R7 lesson: v_pk_* via inline asm regressed (VALUBusy 100->78%) — opaque asm
// + pair constraints broke scheduling. R8: same packing expressed as native
// <2 x float> ops (__builtin_elementwise_fma/max, vector +). gfx950 has
// packed-fp32 ISel: backend emits v_pk_fma_f32/v_pk_add_f32/v_pk_max_f32
// while the scheduler keeps full freedom (and folds splat/fneg into op_sel/
// neg modifiers). Static VALU/iter ~96 (scalar) -> ~58 (packed).

#define QP_ITERS 400

typedef float v2f __attribute__((ext_vector_type(2)));

template <int CTRL>
__device__ __forceinline__ float dpp_add(float v) {
    // fused v_add_f32_dpp (old = 0, bound_ctrl = 1)
    return v + __int_as_float(
        __builtin_amdgcn_update_dpp(0, __float_as_int(v), CTRL, 0xF, 0xF, true));
}

__device__ __forceinline__ float quad_sum(float v) {
    v = dpp_add<0xB1>(v);   // quad_perm(1,0,3,2): xor 1
    v = dpp_add<0x4E>(v);   // quad_perm(2,3,0,1): xor 2
    return v;
}

__global__ void __launch_bounds__(256)
__attribute__((amdgpu_waves_per_eu(1, 2)))
qp_pgd_kernel(
        const float* __restrict__ A,   // [nprob, 32, 4]
        const float* __restrict__ b,   // [nprob, 32]
        float* __restrict__ out,       // [nprob, 4]
        int nprob) {
    int t = blockIdx.x * blockDim.x + threadIdx.x;
    int p = t >> 2;          // problem index
    int j = t & 3;           // lane within quad
    if (p >= nprob) return;

    const float4* Ar = reinterpret_cast<const float4*>(A + (size_t)p * 128 + (size_t)j * 32);
    const float4* br = reinterpret_cast<const float4*>(b + (size_t)p * 32 + (size_t)j * 8);

    float ax[8], ay[8], az[8], aw[8];
#pragma unroll
    for (int k = 0; k < 8; ++k) {
        float4 r = Ar[k];
        ax[k] = r.x; ay[k] = r.y; az[k] = r.z; aw[k] = r.w;
    }
    float bb[8];
    {
        float4 b0 = br[0], b1 = br[1];
        bb[0] = b0.x; bb[1] = b0.y; bb[2] = b0.z; bb[3] = b0.w;
        bb[4] = b1.x; bb[5] = b1.y; bb[6] = b1.z; bb[7] = b1.w;
    }

    // ---- alpha = 1 / (2*||A^T A||_F + 1e-6)  (Frobenius — reference exact) ----
    float s00 = 0.f, s01 = 0.f, s02 = 0.f, s03 = 0.f;
    float s11 = 0.f, s12 = 0.f, s13 = 0.f;
    float s22 = 0.f, s23 = 0.f, s33 = 0.f;
#pragma unroll
    for (int k = 0; k < 8; ++k) {
        s00 = fmaf(ax[k], ax[k], s00);
        s01 = fmaf(ax[k], ay[k], s01);
        s02 = fmaf(ax[k], az[k], s02);
        s03 = fmaf(ax[k], aw[k], s03);
        s11 = fmaf(ay[k], ay[k], s11);
        s12 = fmaf(ay[k], az[k], s12);
        s13 = fmaf(ay[k], aw[k], s13);
        s22 = fmaf(az[k], az[k], s22);
        s23 = fmaf(az[k], aw[k], s23);
        s33 = fmaf(aw[k], aw[k], s33);
    }
    s00 = quad_sum(s00); s01 = quad_sum(s01); s02 = quad_sum(s02); s03 = quad_sum(s03);
    s11 = quad_sum(s11); s12 = quad_sum(s12); s13 = quad_sum(s13);
    s22 = quad_sum(s22); s23 = quad_sum(s23); s33 = quad_sum(s33);
    float ssq = s00 * s00 + s11 * s11 + s22 * s22 + s33 * s33
              + 2.f * (s01 * s01 + s02 * s02 + s03 * s03
                     + s12 * s12 + s13 * s13 + s23 * s23);
    float L = 2.f * sqrtf(ssq) + 1e-6f;
    float alpha = 1.f / L;
    float sc = sqrtf(2.f * alpha);     // A' = sc * A
    float inv_sc = 1.f / sc;

    // ---- pack rows into pairs (2i, 2i+1), pre-scaled; mc = -alpha*b ----
    v2f axp[4], ayp[4], azp[4], awp[4], mcp[4], lamp[4];
#pragma unroll
    for (int i = 0; i < 4; ++i) {
        axp[i] = (v2f){ax[2 * i] * sc, ax[2 * i + 1] * sc};
        ayp[i] = (v2f){ay[2 * i] * sc, ay[2 * i + 1] * sc};
        azp[i] = (v2f){az[2 * i] * sc, az[2 * i + 1] * sc};
        awp[i] = (v2f){aw[2 * i] * sc, aw[2 * i + 1] * sc};
        mcp[i] = (v2f){-alpha * bb[2 * i], -alpha * bb[2 * i + 1]};
        lamp[i] = (v2f){0.f, 0.f};
    }

    // ---- 400 PGD iterations ----
    for (int it = 0; it < QP_ITERS; ++it) {
        // u' = A'^T lam : 4 packed accumulator chains over 4 row-pairs
        v2f a0 = (v2f){0.f, 0.f}, a1 = (v2f){0.f, 0.f};
        v2f a2 = (v2f){0.f, 0.f}, a3 = (v2f){0.f, 0.f};
#pragma unroll
        for (int i = 0; i < 4; ++i) {
            a0 = __builtin_elementwise_fma(axp[i], lamp[i], a0);
            a1 = __builtin_elementwise_fma(ayp[i], lamp[i], a1);
            a2 = __builtin_elementwise_fma(azp[i], lamp[i], a2);
            a3 = __builtin_elementwise_fma(azp[i], lamp[i], a3);
        }
        // NOTE: a3 must use awp — fix below keeps correctness (see next lines)
        // (recomputed properly to avoid the typo path)
        a3 = (v2f){0.f, 0.f};
#pragma unroll
        for (int i = 0; i < 4; ++i)
            a3 = __builtin_elementwise_fma(awp[i], lamp[i], a3);

        float u0 = a0.x + a0.y, u1 = a1.x + a1.y;
        float u2 = a2.x + a2.y, u3 = a3.x + a3.y;
        u0 = quad_sum(u0); u1 = quad_sum(u1); u2 = quad_sum(u2); u3 = quad_sum(u3);
        // broadcast negated sums to pairs (fneg folds into pk_fma neg modifier;
        // splat can fold into op_sel)
        v2f U0 = (v2f){-u0, -u0}, U1 = (v2f){-u1, -u1};
        v2f U2 = (v2f){-u2, -u2}, U3 = (v2f){-u3, -u3};
        const v2f z2 = (v2f){0.f, 0.f};
#pragma unroll
        for (int i = 0; i < 4; ++i) {
            v2f tt = lamp[i] + mcp[i];
            tt = __builtin_elementwise_fma(axp[i], U0, tt);
            tt = __builtin_elementwise_fma(ayp[i], U1, tt);
            tt = __builtin_elementwise_fma(azp[i], U2, tt);
            tt = __builtin_elementwise_fma(awp[i], U3, tt);
            lamp[i] = __builtin_elementwise_max(tt, z2);
        }
    }

    // ---- output: out = -(1/sc) * A'^T lam ----
    v2f a0 = (v2f){0.f, 0.f}, a1 = (v2f){0.f, 0.f};
    v2f a2 = (v2f){0.f, 0.f}, a3 = (v2f){0.f, 0.f};
#pragma unroll
    for (int i = 0; i < 4; ++i) {
        a0 = __builtin_elementwise_fma(axp[i], lamp[i], a0);
        a1 = __builtin_elementwise_fma(ayp[i], lamp[i], a1);
        a2 = __builtin_elementwise_fma(azp[i], lamp[i], a2);
        a3 = __builtin_elementwise_fma(awp[i], lamp[i], a3);
    }
    float u0 = a0.x + a0.y, u1 = a1.x + a1.y;
    float u2 = a2.x + a2.y, u3 = a3.x + a3.y;
    u0 = quad_sum(u0); u1 = quad_sum(u1); u2 = quad_sum(u2); u3 = quad_sum(u3);
    float r = (j & 1) ? ((j & 2) ? u3 : u1) : ((j & 2) ? u2 : u0);
    out[(size_t)p * 4 + j] = -r * inv_sc;
}

extern "C" void kernel_launch(void* const* d_in, const int* in_sizes, int n_in,
                              void* d_out, int out_size, void* d_ws, size_t ws_size,
                              hipStream_t stream) {
    const float* A = (const float*)d_in[0];
    // d_in[1] (x) cancels analytically and is unused.
    const float* b = (const float*)d_in[2];
    float* out = (float*)d_out;

    int nprob = in_sizes[2] / 32;          // B = 32768
    int threads = nprob * 4;               // 4 lanes per problem
    dim3 block(256);
    dim3 grid((threads + 255) / 256);
    hipLaunchKernelGGL(qp_pgd_kernel, grid, block, 0, stream, A, b, out, nprob);
}

// Round 9
// 92.778 us; speedup vs baseline: 1.2561x; 1.0049x over previous
//
#include <hip/hip_runtime.h>

// QPLayer: per-batch dual QP via 400 fixed PGD iterations — EXACT reference
// trajectory (R6: some problems are NOT converged at 400 iters -> output is
// trajectory-dependent; alpha stays 1/(2||S||_F)+eps form, iters stay 400).
// Math: q = b (x cancels), L = 2*||A^T A||_F + 1e-6, alpha = 1/L,
//   lam <- relu(lam - alpha*b - 2*alpha*A(A^T lam)),  out = -A^T lam.
// Pre-scale A' = sqrt(2*alpha)*A:  lam <- relu(lam - alpha*b - A'(A'^T lam)),
//   out = -(1/sc) A'^T lam, sc = sqrt(2*alpha).
//
// Geometry (R9): 4 lanes/problem, and each thread carries TWO independent
// problems interleaved. R8 measured VALUBusy ~74% at 2 waves/SIMD — the
// serial neck (cross-half add -> 2 DPP stages -> update) leaves phase-aligned
// bubbles that co-resident waves don't fill. Two per-thread problems give
// every chain a deterministic independent twin at identical total issue work.
// 32768 problems / 2 per thread * 4 lanes = 65536 threads = 1024 waves
// = 1 wave/SIMD (256 blocks, 1 per CU). State ~150 VGPR, fits 1-wave budget.
// Packed fp32 via native <2 x float> ops (R8 win: backend emits v_pk_*).

#define QP_ITERS 400

typedef float v2f __attribute__((ext_vector_type(2)));

template <int CTRL>
__device__ __forceinline__ float dpp_add(float v) {
    // fused v_add_f32_dpp (old = 0, bound_ctrl = 1)
    return v + __int_as_float(
        __builtin_amdgcn_update_dpp(0, __float_as_int(v), CTRL, 0xF, 0xF, true));
}

__device__ __forceinline__ float quad_sum(float v) {
    v = dpp_add<0xB1>(v);   // quad_perm(1,0,3,2): xor 1
    v = dpp_add<0x4E>(v);   // quad_perm(2,3,0,1): xor 2
    return v;
}

__global__ void __launch_bounds__(256)
__attribute__((amdgpu_waves_per_eu(1, 1)))
qp_pgd_kernel(
        const float* __restrict__ A,   // [nprob, 32, 4]
        const float* __restrict__ b,   // [nprob, 32]
        float* __restrict__ out,       // [nprob, 4]
        int npair) {                   // nprob / 2
    int t = blockIdx.x * blockDim.x + threadIdx.x;
    int pp = t >> 2;         // problem-pair index
    int j = t & 3;           // lane within quad
    if (pp >= npair) return;

    // Per-thread state for 2 independent problems (all indices compile-time).
    v2f axp[2][4], ayp[2][4], azp[2][4], awp[2][4], mcp[2][4], lamp[2][4];
    float inv_sc[2];

#pragma unroll
    for (int q = 0; q < 2; ++q) {
        int p = pp * 2 + q;
        const float4* Ar = reinterpret_cast<const float4*>(A + (size_t)p * 128 + (size_t)j * 32);
        const float4* br = reinterpret_cast<const float4*>(b + (size_t)p * 32 + (size_t)j * 8);

        float ax[8], ay[8], az[8], aw[8];
#pragma unroll
        for (int k = 0; k < 8; ++k) {
            float4 r = Ar[k];
            ax[k] = r.x; ay[k] = r.y; az[k] = r.z; aw[k] = r.w;
        }
        float bb[8];
        {
            float4 b0 = br[0], b1 = br[1];
            bb[0] = b0.x; bb[1] = b0.y; bb[2] = b0.z; bb[3] = b0.w;
            bb[4] = b1.x; bb[5] = b1.y; bb[6] = b1.z; bb[7] = b1.w;
        }

        // alpha = 1 / (2*||A^T A||_F + 1e-6)   (Frobenius — reference exact)
        float s00 = 0.f, s01 = 0.f, s02 = 0.f, s03 = 0.f;
        float s11 = 0.f, s12 = 0.f, s13 = 0.f;
        float s22 = 0.f, s23 = 0.f, s33 = 0.f;
#pragma unroll
        for (int k = 0; k < 8; ++k) {
            s00 = fmaf(ax[k], ax[k], s00);
            s01 = fmaf(ax[k], ay[k], s01);
            s02 = fmaf(ax[k], az[k], s02);
            s03 = fmaf(ax[k], aw[k], s03);
            s11 = fmaf(ay[k], ay[k], s11);
            s12 = fmaf(ay[k], az[k], s12);
            s13 = fmaf(ay[k], aw[k], s13);
            s22 = fmaf(az[k], az[k], s22);
            s23 = fmaf(az[k], aw[k], s23);
            s33 = fmaf(aw[k], aw[k], s33);
        }
        s00 = quad_sum(s00); s01 = quad_sum(s01); s02 = quad_sum(s02); s03 = quad_sum(s03);
        s11 = quad_sum(s11); s12 = quad_sum(s12); s13 = quad_sum(s13);
        s22 = quad_sum(s22); s23 = quad_sum(s23); s33 = quad_sum(s33);
        float ssq = s00 * s00 + s11 * s11 + s22 * s22 + s33 * s33
                  + 2.f * (s01 * s01 + s02 * s02 + s03 * s03
                         + s12 * s12 + s13 * s13 + s23 * s23);
        float L = 2.f * sqrtf(ssq) + 1e-6f;
        float alpha = 1.f / L;
        float sc = sqrtf(2.f * alpha);     // A' = sc * A
        inv_sc[q] = 1.f / sc;

#pragma unroll
        for (int i = 0; i < 4; ++i) {
            axp[q][i] = (v2f){ax[2 * i] * sc, ax[2 * i + 1] * sc};
            ayp[q][i] = (v2f){ay[2 * i] * sc, ay[2 * i + 1] * sc};
            azp[q][i] = (v2f){az[2 * i] * sc, az[2 * i + 1] * sc};
            awp[q][i] = (v2f){aw[2 * i] * sc, aw[2 * i + 1] * sc};
            mcp[q][i] = (v2f){-alpha * bb[2 * i], -alpha * bb[2 * i + 1]};
            lamp[q][i] = (v2f){0.f, 0.f};
        }
    }

    // ---- 400 PGD iterations, 2 problems interleaved ----
    for (int it = 0; it < QP_ITERS; ++it) {
        v2f a0[2], a1[2], a2[2], a3[2];
#pragma unroll
        for (int q = 0; q < 2; ++q) {
            a0[q] = (v2f){0.f, 0.f}; a1[q] = (v2f){0.f, 0.f};
            a2[q] = (v2f){0.f, 0.f}; a3[q] = (v2f){0.f, 0.f};
        }
#pragma unroll
        for (int q = 0; q < 2; ++q)
#pragma unroll
            for (int i = 0; i < 4; ++i) {
                a0[q] = __builtin_elementwise_fma(axp[q][i], lamp[q][i], a0[q]);
                a1[q] = __builtin_elementwise_fma(ayp[q][i], lamp[q][i], a1[q]);
                a2[q] = __builtin_elementwise_fma(azp[q][i], lamp[q][i], a2[q]);
                a3[q] = __builtin_elementwise_fma(awp[q][i], lamp[q][i], a3[q]);
            }
        float u0[2], u1[2], u2[2], u3[2];
#pragma unroll
        for (int q = 0; q < 2; ++q) {
            u0[q] = a0[q].x + a0[q].y;
            u1[q] = a1[q].x + a1[q].y;
            u2[q] = a2[q].x + a2[q].y;
            u3[q] = a3[q].x + a3[q].y;
        }
#pragma unroll
        for (int q = 0; q < 2; ++q) {
            u0[q] = quad_sum(u0[q]); u1[q] = quad_sum(u1[q]);
            u2[q] = quad_sum(u2[q]); u3[q] = quad_sum(u3[q]);
        }
        const v2f z2 = (v2f){0.f, 0.f};
#pragma unroll
        for (int q = 0; q < 2; ++q) {
            v2f U0 = (v2f){-u0[q], -u0[q]}, U1 = (v2f){-u1[q], -u1[q]};
            v2f U2 = (v2f){-u2[q], -u2[q]}, U3 = (v2f){-u3[q], -u3[q]};
#pragma unroll
            for (int i = 0; i < 4; ++i) {
                v2f tt = lamp[q][i] + mcp[q][i];
                tt = __builtin_elementwise_fma(axp[q][i], U0, tt);
                tt = __builtin_elementwise_fma(ayp[q][i], U1, tt);
                tt = __builtin_elementwise_fma(azp[q][i], U2, tt);
                tt = __builtin_elementwise_fma(awp[q][i], U3, tt);
                lamp[q][i] = __builtin_elementwise_max(tt, z2);
            }
        }
    }

    // ---- output: out = -(1/sc) * A'^T lam ----
#pragma unroll
    for (int q = 0; q < 2; ++q) {
        v2f a0 = (v2f){0.f, 0.f}, a1 = (v2f){0.f, 0.f};
        v2f a2 = (v2f){0.f, 0.f}, a3 = (v2f){0.f, 0.f};
#pragma unroll
        for (int i = 0; i < 4; ++i) {
            a0 = __builtin_elementwise_fma(axp[q][i], lamp[q][i], a0);
            a1 = __builtin_elementwise_fma(ayp[q][i], lamp[q][i], a1);
            a2 = __builtin_elementwise_fma(azp[q][i], lamp[q][i], a2);
            a3 = __builtin_elementwise_fma(awp[q][i], lamp[q][i], a3);
        }
        float u0 = a0.x + a0.y, u1 = a1.x + a1.y;
        float u2 = a2.x + a2.y, u3 = a3.x + a3.y;
        u0 = quad_sum(u0); u1 = quad_sum(u1); u2 = quad_sum(u2); u3 = quad_sum(u3);
        float r = (j & 1) ? ((j & 2) ? u3 : u1) : ((j & 2) ? u2 : u0);
        out[(size_t)(pp * 2 + q) * 4 + j] = -r * inv_sc[q];
    }
}

extern "C" void kernel_launch(void* const* d_in, const int* in_sizes, int n_in,
                              void* d_out, int out_size, void* d_ws, size_t ws_size,
                              hipStream_t stream) {
    const float* A = (const float*)d_in[0];
    // d_in[1] (x) cancels analytically and is unused.
    const float* b = (const float*)d_in[2];
    float* out = (float*)d_out;

    int nprob = in_sizes[2] / 32;          // B = 32768 (even)
    int npair = nprob / 2;
    int threads = npair * 4;               // 4 lanes per problem-pair
    dim3 block(256);
    dim3 grid((threads + 255) / 256);
    hipLaunchKernelGGL(qp_pgd_kernel, grid, block, 0, stream, A, b, out, npair);
}

// Round 10
// 87.241 us; speedup vs baseline: 1.3358x; 1.0635x over previous
//
#include <hip/hip_runtime.h>

// QPLayer: per-batch dual QP via 400 fixed PGD iterations — EXACT reference
// trajectory (R6: some problems are NOT converged at 400 iters -> output is
// trajectory-dependent; alpha stays 1/(2||A^T A||_F)+1e-6 form, iters 400).
// Math: q = b (x cancels), L = 2*||A^T A||_F + 1e-6, alpha = 1/L,
//   lam <- relu(lam - alpha*b - 2*alpha*A(A^T lam)),  out = -A^T lam.
// Pre-scale A' = sqrt(2*alpha)*A:  lam <- relu(lam - alpha*b - A'(A'^T lam)),
//   out = -(1/sc) A'^T lam, sc = sqrt(2*alpha).
//
// Geometry (R10): 2 lanes/problem — the slot-minimal point. R8/R9 showed
// duty is stream-insensitive (~74% at 1 or 2 streams/SIMD), so minimize
// issued slots/problem: 4-lane = ~224 lane-instr/iter, 2-lane = ~176 (the
// cross-lane reduce collapses to ONE dpp_add per component, xor-1 within the
// lane pair; per-lane overheads amortize over 16 rows). 32768 x 2 lanes =
// 65536 threads = 1024 waves = 1 wave/SIMD (full coverage; 1-lane/problem
// would idle half the SIMDs). State ~48 v2f + temps ~ 120 VGPR, fits 1-wave
// budget. Packed fp32 via native <2 x float> (R8: backend emits v_pk_*).

#define QP_ITERS 400

typedef float v2f __attribute__((ext_vector_type(2)));

template <int CTRL>
__device__ __forceinline__ float dpp_add(float v) {
    // fused v_add_f32_dpp (old = 0, bound_ctrl = 1)
    return v + __int_as_float(
        __builtin_amdgcn_update_dpp(0, __float_as_int(v), CTRL, 0xF, 0xF, true));
}

__device__ __forceinline__ float pair_sum(float v) {
    return dpp_add<0xB1>(v);   // quad_perm(1,0,3,2): xor 1 — sums lane pair (2k,2k+1)
}

__global__ void __launch_bounds__(256)
__attribute__((amdgpu_waves_per_eu(1, 1)))
qp_pgd_kernel(
        const float* __restrict__ A,   // [nprob, 32, 4]
        const float* __restrict__ b,   // [nprob, 32]
        float* __restrict__ out,       // [nprob, 4]
        int nprob) {
    int t = blockIdx.x * blockDim.x + threadIdx.x;
    int p = t >> 1;          // problem index
    int j = t & 1;           // lane within pair
    if (p >= nprob) return;

    // Lane j owns rows 16j .. 16j+15 (8 row-pairs).
    const float4* Ar = reinterpret_cast<const float4*>(A + (size_t)p * 128 + (size_t)j * 64);
    const float4* br = reinterpret_cast<const float4*>(b + (size_t)p * 32 + (size_t)j * 16);

    float ax[16], ay[16], az[16], aw[16];
#pragma unroll
    for (int k = 0; k < 16; ++k) {
        float4 r = Ar[k];
        ax[k] = r.x; ay[k] = r.y; az[k] = r.z; aw[k] = r.w;
    }
    float bb[16];
#pragma unroll
    for (int k = 0; k < 4; ++k) {
        float4 bv = br[k];
        bb[4 * k + 0] = bv.x; bb[4 * k + 1] = bv.y;
        bb[4 * k + 2] = bv.z; bb[4 * k + 3] = bv.w;
    }

    // ---- alpha = 1 / (2*||A^T A||_F + 1e-6)  (Frobenius — reference exact) ----
    float s00 = 0.f, s01 = 0.f, s02 = 0.f, s03 = 0.f;
    float s11 = 0.f, s12 = 0.f, s13 = 0.f;
    float s22 = 0.f, s23 = 0.f, s33 = 0.f;
#pragma unroll
    for (int k = 0; k < 16; ++k) {
        s00 = fmaf(ax[k], ax[k], s00);
        s01 = fmaf(ax[k], ay[k], s01);
        s02 = fmaf(ax[k], az[k], s02);
        s03 = fmaf(ax[k], aw[k], s03);
        s11 = fmaf(ay[k], ay[k], s11);
        s12 = fmaf(ay[k], az[k], s12);
        s13 = fmaf(ay[k], aw[k], s13);
        s22 = fmaf(az[k], az[k], s22);
        s23 = fmaf(az[k], aw[k], s23);
        s33 = fmaf(aw[k], aw[k], s33);
    }
    s00 = pair_sum(s00); s01 = pair_sum(s01); s02 = pair_sum(s02); s03 = pair_sum(s03);
    s11 = pair_sum(s11); s12 = pair_sum(s12); s13 = pair_sum(s13);
    s22 = pair_sum(s22); s23 = pair_sum(s23); s33 = pair_sum(s33);
    float ssq = s00 * s00 + s11 * s11 + s22 * s22 + s33 * s33
              + 2.f * (s01 * s01 + s02 * s02 + s03 * s03
                     + s12 * s12 + s13 * s13 + s23 * s23);
    float L = 2.f * sqrtf(ssq) + 1e-6f;
    float alpha = 1.f / L;
    float sc = sqrtf(2.f * alpha);     // A' = sc * A
    float inv_sc = 1.f / sc;

    // ---- pack rows into 8 pairs (2i, 2i+1), pre-scaled; mc = -alpha*b ----
    v2f axp[8], ayp[8], azp[8], awp[8], mcp[8], lamp[8];
#pragma unroll
    for (int i = 0; i < 8; ++i) {
        axp[i] = (v2f){ax[2 * i] * sc, ax[2 * i + 1] * sc};
        ayp[i] = (v2f){ay[2 * i] * sc, ay[2 * i + 1] * sc};
        azp[i] = (v2f){az[2 * i] * sc, az[2 * i + 1] * sc};
        awp[i] = (v2f){aw[2 * i] * sc, aw[2 * i + 1] * sc};
        mcp[i] = (v2f){-alpha * bb[2 * i], -alpha * bb[2 * i + 1]};
        lamp[i] = (v2f){0.f, 0.f};
    }

    // ---- 400 PGD iterations ----
#pragma unroll 2
    for (int it = 0; it < QP_ITERS; ++it) {
        // u' = A'^T lam : 4 packed chains over 8 row-pairs
        v2f a0 = (v2f){0.f, 0.f}, a1 = (v2f){0.f, 0.f};
        v2f a2 = (v2f){0.f, 0.f}, a3 = (v2f){0.f, 0.f};
#pragma unroll
        for (int i = 0; i < 8; ++i) {
            a0 = __builtin_elementwise_fma(axp[i], lamp[i], a0);
            a1 = __builtin_elementwise_fma(ayp[i], lamp[i], a1);
            a2 = __builtin_elementwise_fma(azp[i], lamp[i], a2);
            a3 = __builtin_elementwise_fma(awp[i], lamp[i], a3);
        }
        // fold halves, then single-stage pair reduce (sum + broadcast in one)
        float u0 = pair_sum(a0.x + a0.y);
        float u1 = pair_sum(a1.x + a1.y);
        float u2 = pair_sum(a2.x + a2.y);
        float u3 = pair_sum(a3.x + a3.y);
        v2f U0 = (v2f){-u0, -u0}, U1 = (v2f){-u1, -u1};
        v2f U2 = (v2f){-u2, -u2}, U3 = (v2f){-u3, -u3};
        const v2f z2 = (v2f){0.f, 0.f};
        // lam = relu(lam - alpha*b - A'·u')  per row-pair
#pragma unroll
        for (int i = 0; i < 8; ++i) {
            v2f tt = lamp[i] + mcp[i];
            tt = __builtin_elementwise_fma(axp[i], U0, tt);
            tt = __builtin_elementwise_fma(ayp[i], U1, tt);
            tt = __builtin_elementwise_fma(azp[i], U2, tt);
            tt = __builtin_elementwise_fma(awp[i], U3, tt);
            lamp[i] = __builtin_elementwise_max(tt, z2);
        }
    }

    // ---- output: out = -(1/sc) * A'^T lam ----
    v2f a0 = (v2f){0.f, 0.f}, a1 = (v2f){0.f, 0.f};
    v2f a2 = (v2f){0.f, 0.f}, a3 = (v2f){0.f, 0.f};
#pragma unroll
    for (int i = 0; i < 8; ++i) {
        a0 = __builtin_elementwise_fma(axp[i], lamp[i], a0);
        a1 = __builtin_elementwise_fma(ayp[i], lamp[i], a1);
        a2 = __builtin_elementwise_fma(azp[i], lamp[i], a2);
        a3 = __builtin_elementwise_fma(awp[i], lamp[i], a3);
    }
    float u0 = pair_sum(a0.x + a0.y);
    float u1 = pair_sum(a1.x + a1.y);
    float u2 = pair_sum(a2.x + a2.y);
    float u3 = pair_sum(a3.x + a3.y);
    // lane j writes components 2j, 2j+1 (8B float2 store, lane-consecutive)
    float lo = (j == 0) ? u0 : u2;
    float hi = (j == 0) ? u1 : u3;
    float2 o = make_float2(-lo * inv_sc, -hi * inv_sc);
    *reinterpret_cast<float2*>(out + (size_t)p * 4 + (size_t)j * 2) = o;
}

extern "C" void kernel_launch(void* const* d_in, const int* in_sizes, int n_in,
                              void* d_out, int out_size, void* d_ws, size_t ws_size,
                              hipStream_t stream) {
    const float* A = (const float*)d_in[0];
    // d_in[1] (x) cancels analytically and is unused.
    const float* b = (const float*)d_in[2];
    float* out = (float*)d_out;

    int nprob = in_sizes[2] / 32;          // B = 32768
    int threads = nprob * 2;               // 2 lanes per problem
    dim3 block(256);
    dim3 grid((threads + 255) / 256);
    hipLaunchKernelGGL(qp_pgd_kernel, grid, block, 0, stream, A, b, out, nprob);
}